// Round 13
// baseline (178.344 us; speedup 1.0000x reference)
//
#include <hip/hip_runtime.h>
#include <hip/hip_bf16.h>
#include <stdint.h>

// LSTM cell as one fused bf16 MFMA GEMM:
//   gates(8192 x 4096) = A(8192 x 2048) @ Bp(4096 x 2048)^T, fused LSTM epilogue.
// A = [x | h_prev] bf16.  Bp rows gate-interleaved per 16 hidden units:
//   packed row r = (h/16)*64 + g*16 + (h%16) -> wave's 4 N-frags = 4 gates of same h.
//
// ROUND 13: fixes R11/R12's cross-wave race. Root cause: vmcnt is PER-WAVE,
// buffers are BLOCK-shared. R11/R12 read buf^1 after the wave's own vmcnt but
// BEFORE the barrier -> wave 0 read rows staged by wave 1 whose loads hadn't
// landed. The barrier after vmcnt is what makes the guarantee collective
// (every passing round had read-after-vmcnt+barrier).
// Schedule per K-tile (BUF = KT&1), 2 blocks/CU (256x128, BK=32, 4 waves, 48KB):
//   p0: MFMA(mh0,AQa,BQcur) | stage A(T+2)+B(T+2)->buf[BUF] (6 loads)
//       | vmcnt(6)  [retires exactly tile T+1's 6 loads]   | pin bar pin
//   p1: MFMA(mh1,AQb,BQcur) | read AQa,AQb,BQnext <- buf[BUF^1] (tile T+1,
//       collectively landed)                                | pin bar pin
// Slot-safety: all reads of buf[T] happen at p1(T-1); stages into buf[T]
// (for T+2) issue at p0(T) -> >=1 barrier margin (R7-proven). Load distance
// issue->retire = 2 phases for both A and B. 6 loads/tile uniform (tail
// clamped -> dupes rewrite identical bytes or land in dead slots).
// BK=32 swizzle: phys chunk = k_chunk ^ ((row>>1)&3); balanced 8 lanes per
// 4-bank group on ds_read_b128 (bandwidth floor, no extra conflict); stage
// source pre-swizzled with the same involution (l&3)^((l>>3)&3).

#define B_DIM 8192
#define I_DIM 1024
#define H_DIM 1024
#define K_DIM 2048   // I + H
#define N_DIM 4096   // 4 gates * H
#define NKT   64     // K_DIM / 32

typedef short bf16x8 __attribute__((ext_vector_type(8)));
typedef float f32x4 __attribute__((ext_vector_type(4)));

__device__ __forceinline__ unsigned short f2bf(float f) {
  unsigned int u = __float_as_uint(f);
  u += 0x7FFFu + ((u >> 16) & 1u);   // RNE
  return (unsigned short)(u >> 16);
}

// ---- merged pack: A = [x|h] -> bf16 row-major (B_DIM,K_DIM);
//      B = 8 weight mats -> bf16 (N_DIM,K_DIM), gate-interleaved rows ----
__global__ void pack_AB_kernel(const float* __restrict__ x, const float* __restrict__ h,
                               const float* __restrict__ Wxi, const float* __restrict__ Whi,
                               const float* __restrict__ Wxf, const float* __restrict__ Whf,
                               const float* __restrict__ Wxc, const float* __restrict__ Whc,
                               const float* __restrict__ Wxo, const float* __restrict__ Who,
                               unsigned short* __restrict__ outA,
                               unsigned short* __restrict__ outB) {
  const int totalA = B_DIM * K_DIM / 8;             // 2M 16B-units
  const int total  = totalA + N_DIM * K_DIM / 8;    // +1M
  for (int idx = blockIdx.x * blockDim.x + threadIdx.x; idx < total;
       idx += gridDim.x * blockDim.x) {
    const float* src;
    unsigned short* dst;
    if (idx < totalA) {
      int row = idx >> 8;              // K_DIM/8 = 256 units/row
      int col = (idx & 255) * 8;
      src = (col < I_DIM) ? (x + (size_t)row * I_DIM + col)
                          : (h + (size_t)row * H_DIM + (col - I_DIM));
      dst = outA + (size_t)idx * 8;
    } else {
      int u2 = idx - totalA;
      int r = u2 >> 8;
      int k = (u2 & 255) * 8;
      int g = (r >> 4) & 3;
      int hh = ((r >> 6) << 4) | (r & 15);
      src = (k < I_DIM)
          ? ((g == 0 ? Wxi : g == 1 ? Wxf : g == 2 ? Wxc : Wxo) + (size_t)hh * I_DIM + k)
          : ((g == 0 ? Whi : g == 1 ? Whf : g == 2 ? Whc : Who) + (size_t)hh * H_DIM + (k - I_DIM));
      dst = outB + (size_t)u2 * 8;
    }
    const float4* s4 = (const float4*)src;
    float4 v0 = s4[0], v1 = s4[1];
    bf16x8 o;
    o[0] = f2bf(v0.x); o[1] = f2bf(v0.y); o[2] = f2bf(v0.z); o[3] = f2bf(v0.w);
    o[4] = f2bf(v1.x); o[5] = f2bf(v1.y); o[6] = f2bf(v1.z); o[7] = f2bf(v1.w);
    *(bf16x8*)dst = o;
  }
}

// ---- GEMM 256x128 tile, BK=32, 4 waves (2Mx2N), 48KB LDS, 2 blocks/CU ----
// LDS map (bytes): A[buf] = buf*16384 (256 rows x 64B)        (0..32768)
//                  B[buf] = 32768 + buf*8192 (128 rows x 64B) (32768..49152)

#define STAGE_A(BUF, KT) do {                                                     \
    int _ktc = (KT) < NKT ? (KT) : (NKT - 1);                                     \
    _Pragma("unroll") for (int i = 0; i < 4; ++i)                                 \
      __builtin_amdgcn_global_load_lds(                                           \
          (const __attribute__((address_space(1))) void*)(gAs + (size_t)i * 16 * K_DIM + (size_t)_ktc * 32), \
          (__attribute__((address_space(3))) void*)(lds + (BUF) * 16384 + wid * 4096 + i * 1024), \
          16, 0, 0);                                                              \
  } while (0)

#define STAGE_B(BUF, KT) do {                                                     \
    int _ktc = (KT) < NKT ? (KT) : (NKT - 1);                                     \
    _Pragma("unroll") for (int i = 0; i < 2; ++i)                                 \
      __builtin_amdgcn_global_load_lds(                                           \
          (const __attribute__((address_space(1))) void*)(gBs + (size_t)i * 16 * K_DIM + (size_t)_ktc * 32), \
          (__attribute__((address_space(3))) void*)(lds + 32768 + (BUF) * 8192 + wid * 2048 + i * 1024), \
          16, 0, 0);                                                              \
  } while (0)

// phase (MH): 16 independent MFMAs, acc rows MH*4..MH*4+3
#define MFMAP(MH, AR, BR)                                                         \
  _Pragma("unroll") for (int mf = 0; mf < 4; ++mf)                                \
  _Pragma("unroll") for (int nn = 0; nn < 4; ++nn)                                \
    acc[(MH)*4 + mf][nn] = __builtin_amdgcn_mfma_f32_16x16x32_bf16(               \
        AR[mf], BR[nn], acc[(MH)*4 + mf][nn], 0, 0, 0)

#define RD_AQ(DST, MH, BUF)                                                       \
  _Pragma("unroll") for (int mf = 0; mf < 4; ++mf)                                \
    DST[mf] = *(const bf16x8*)(ldsAr + (BUF) * 16384 + ((MH)*4 + mf) * 1024);

#define RD_BQ(DST, BUF)                                                           \
  _Pragma("unroll") for (int nn = 0; nn < 4; ++nn)                                \
    DST[nn] = *(const bf16x8*)(ldsBr + (BUF) * 8192 + nn * 1024);

#define KTILE(BUF, KT, BQcur, BQnext) do {                                        \
    /* p0: MFMA mh0 | stage tile KT+2 (6 loads) | vmcnt(6) -> T+1 retired */      \
    __builtin_amdgcn_s_setprio(1);                                                \
    MFMAP(0, AQa, BQcur);                                                         \
    __builtin_amdgcn_s_setprio(0);                                                \
    STAGE_A((BUF), (KT) + 2);                                                     \
    STAGE_B((BUF), (KT) + 2);                                                     \
    asm volatile("s_waitcnt vmcnt(6)" ::: "memory");                              \
    __builtin_amdgcn_sched_barrier(0);                                            \
    __builtin_amdgcn_s_barrier();                                                 \
    __builtin_amdgcn_sched_barrier(0);                                            \
    /* p1: MFMA mh1 | pre-read ALL tile KT+1 operands from buf^1 (landed) */      \
    __builtin_amdgcn_s_setprio(1);                                                \
    MFMAP(1, AQb, BQcur);                                                         \
    __builtin_amdgcn_s_setprio(0);                                                \
    RD_AQ(AQa, 0, (BUF) ^ 1);                                                     \
    RD_AQ(AQb, 1, (BUF) ^ 1);                                                     \
    RD_BQ(BQnext, (BUF) ^ 1);                                                     \
    __builtin_amdgcn_sched_barrier(0);                                            \
    __builtin_amdgcn_s_barrier();                                                 \
    __builtin_amdgcn_sched_barrier(0);                                            \
  } while (0)

__launch_bounds__(256, 2)
__global__ void lstm_gemm_kernel(const unsigned short* __restrict__ A,
                                 const unsigned short* __restrict__ Bp,
                                 const float* __restrict__ c_prev,
                                 const float* __restrict__ bxi, const float* __restrict__ bhi,
                                 const float* __restrict__ bxf, const float* __restrict__ bhf,
                                 const float* __restrict__ bxc, const float* __restrict__ bhc,
                                 const float* __restrict__ bxo, const float* __restrict__ bho,
                                 float* __restrict__ out) {
  __shared__ __align__(16) char lds[49152];

  // XCD-aware bijective swizzle (1024 % 8 == 0)
  const int nwg = gridDim.x;
  int bid = blockIdx.x;
  int q = nwg >> 3;
  int wg = (bid & 7) * q + (bid >> 3);
  int bm = wg >> 5;          // 32 M-tiles (256 rows)
  int bn = wg & 31;          // 32 N-tiles (128 cols)

  int tid = threadIdx.x;
  int lane = tid & 63;
  int wid = tid >> 6;        // 4 waves
  int wm = wid >> 1;         // 2 M-wave rows (128 rows each)
  int wn = wid & 1;          // 2 N-wave cols (64 cols each)

  // ---- staging global sources (pre-swizzled chunk: (l&3)^((l>>3)&3)) ----
  int swc = (lane & 3) ^ ((lane >> 3) & 3);
  const unsigned short* gAs = A  + (size_t)(bm * 256 + wid * 64 + (lane >> 2)) * K_DIM + swc * 8;
  const unsigned short* gBs = Bp + (size_t)(bn * 128 + wid * 32 + (lane >> 2)) * K_DIM + swc * 8;

  // ---- LDS read bases; phys chunk = kl ^ ((c15>>1)&3) ----
  int c15 = lane & 15;
  int kl = lane >> 4;                   // k-group 0..3 (8 bf16 each)
  int rdsw = ((kl ^ ((c15 >> 1) & 3)) << 4);
  const char* ldsAr = lds + wm * 8192 + c15 * 64 + rdsw;
  const char* ldsBr = lds + 32768 + wn * 4096 + c15 * 64 + rdsw;

  f32x4 acc[8][4];
  f32x4 zero = {0.f, 0.f, 0.f, 0.f};
#pragma unroll
  for (int m = 0; m < 8; ++m)
#pragma unroll
    for (int n = 0; n < 4; ++n) acc[m][n] = zero;

  bf16x8 AQa[4], AQb[4];   // A mh0 / mh1 fragments for the CURRENT tile
  bf16x8 BQa[4], BQb[4];   // B ping/pong (4 n-frags each)

  // ---- prologue: tile0 -> buf0 (6 loads), tile1 -> buf1 (6 loads);
  // vmcnt(6) -> tile0 landed collectively after barrier; pre-read ALL of
  // tile0's operands; extra barrier so first-loop stages into buf0 are
  // barrier-separated from these reads. ----
  STAGE_A(0, 0);
  STAGE_B(0, 0);
  STAGE_A(1, 1);
  STAGE_B(1, 1);
  asm volatile("s_waitcnt vmcnt(6)" ::: "memory");
  __builtin_amdgcn_s_barrier();
  __builtin_amdgcn_sched_barrier(0);
  RD_AQ(AQa, 0, 0);
  RD_AQ(AQb, 1, 0);
  RD_BQ(BQa, 0);
  __builtin_amdgcn_sched_barrier(0);
  __builtin_amdgcn_s_barrier();
  __builtin_amdgcn_sched_barrier(0);

#pragma unroll 1
  for (int kt = 0; kt < NKT; kt += 2) {
    KTILE(0, kt, BQa, BQb);
    KTILE(1, kt + 1, BQb, BQa);
  }

  // ---- fused LSTM epilogue: lane owns hidden unit h; acc[mi][g][j] = gate g ----
  int h = (bn * 2 + wn) * 16 + c15;
  float bi = bxi[h] + bhi[h];
  float bf_ = bxf[h] + bhf[h];
  float bc = bxc[h] + bhc[h];
  float bo = bxo[h] + bho[h];
  int row0 = bm * 256 + wm * 128 + kl * 4;
#pragma unroll
  for (int mi = 0; mi < 8; ++mi) {
#pragma unroll
    for (int j = 0; j < 4; ++j) {
      int r = row0 + mi * 16 + j;
      size_t off = (size_t)r * H_DIM + h;
      float zi = acc[mi][0][j] + bi;
      float zf = acc[mi][1][j] + bf_;
      float zc = acc[mi][2][j] + bc;
      float zo = acc[mi][3][j] + bo;
      float ig = 1.f / (1.f + __expf(-zi));
      float fg = 1.f / (1.f + __expf(-zf));
      float e2 = __expf(-2.f * zc);
      float gg = (1.f - e2) / (1.f + e2);       // tanh(zc)
      float og = 1.f / (1.f + __expf(-zo));
      float cp = c_prev[off];
      float cn = fg * cp + ig * gg;
      float e2c = __expf(-2.f * cn);
      float th = (1.f - e2c) / (1.f + e2c);     // tanh(cn)
      out[off] = og * th;                        // h_new
      out[(size_t)B_DIM * H_DIM + off] = cn;     // c_new
    }
  }
}

extern "C" void kernel_launch(void* const* d_in, const int* in_sizes, int n_in,
                              void* d_out, int out_size, void* d_ws, size_t ws_size,
                              hipStream_t stream) {
  const float* x      = (const float*)d_in[0];
  const float* h_prev = (const float*)d_in[1];
  const float* c_prev = (const float*)d_in[2];
  const float* Wxi = (const float*)d_in[3];
  const float* Whi = (const float*)d_in[4];
  const float* Wxf = (const float*)d_in[5];
  const float* Whf = (const float*)d_in[6];
  const float* Wxc = (const float*)d_in[7];
  const float* Whc = (const float*)d_in[8];
  const float* Wxo = (const float*)d_in[9];
  const float* Who = (const float*)d_in[10];
  const float* bxi = (const float*)d_in[11];
  const float* bhi = (const float*)d_in[12];
  const float* bxf = (const float*)d_in[13];
  const float* bhf = (const float*)d_in[14];
  const float* bxc = (const float*)d_in[15];
  const float* bhc = (const float*)d_in[16];
  const float* bxo = (const float*)d_in[17];
  const float* bho = (const float*)d_in[18];

  unsigned short* Abf = (unsigned short*)d_ws;                                      // 32 MiB
  unsigned short* Bbf = (unsigned short*)((char*)d_ws + (size_t)B_DIM * K_DIM * 2); // +16 MiB

  pack_AB_kernel<<<2048, 256, 0, stream>>>(x, h_prev,
      Wxi, Whi, Wxf, Whf, Wxc, Whc, Wxo, Who, Abf, Bbf);
  lstm_gemm_kernel<<<1024, 256, 0, stream>>>(Abf, Bbf, c_prev,
      bxi, bhi, bxf, bhf, bxc, bhc, bxo, bho, (float*)d_out);
}

// Round 14
// 151.455 us; speedup vs baseline: 1.1775x; 1.1775x over previous
//
#include <hip/hip_runtime.h>
#include <hip/hip_bf16.h>
#include <stdint.h>

// LSTM cell as one fused bf16 MFMA GEMM (R10/R7 schedule — session best: 152.7us):
//   gates(8192 x 4096) = A(8192 x 2048) @ Bp(4096 x 2048)^T, fused LSTM epilogue.
// A = [x | h_prev] bf16.  Bp rows gate-interleaved per 16 hidden units:
//   packed row r = (h/16)*64 + g*16 + (h%16) -> wave's 4 N-frags = 4 gates of same h.
//
// FINAL (round 14): revert to the banked best (round 10). Session findings:
//  - R7/R10 GEMM: 256x256 tile, BK=64, 8 waves, MFMA-first 4 phases/K-tile,
//    operands read one phase ahead (ping-pong regs), counted vmcnt, 1 bar/phase
//    -> ~1083 TF warm (43% dense peak), ~35% cold MfmaUtil.
//  - Six schedule variants (8-phase, uniform-stage, reg-pipeline, balanced,
//    B-in-reg, 2-blocks/CU) all pinned at 30-35% cold util: the plateau is the
//    co-designed-schedule gap (guide m232 OPEN quadrant), not a resource pipe.
//  - vmcnt lessons: (1) plain loads interleaved with global_load_lds couple
//    completion (in-order queue) -> R9 -46%; (2) vmcnt is PER-WAVE; cross-wave
//    LDS visibility requires vmcnt THEN barrier before reading sibling-staged
//    slots (R11/R12 race).
//  - Pack: merged single kernel, HBM-roofline (~26us for 144MB).

#define B_DIM 8192
#define I_DIM 1024
#define H_DIM 1024
#define K_DIM 2048   // I + H
#define N_DIM 4096   // 4 gates * H
#define NKT   32     // K_DIM / 64

typedef short bf16x8 __attribute__((ext_vector_type(8)));
typedef float f32x4 __attribute__((ext_vector_type(4)));

__device__ __forceinline__ unsigned short f2bf(float f) {
  unsigned int u = __float_as_uint(f);
  u += 0x7FFFu + ((u >> 16) & 1u);   // RNE
  return (unsigned short)(u >> 16);
}

// ---- merged pack: A = [x|h] -> bf16 row-major (B_DIM,K_DIM);
//      B = 8 weight mats -> bf16 (N_DIM,K_DIM), gate-interleaved rows ----
__global__ void pack_AB_kernel(const float* __restrict__ x, const float* __restrict__ h,
                               const float* __restrict__ Wxi, const float* __restrict__ Whi,
                               const float* __restrict__ Wxf, const float* __restrict__ Whf,
                               const float* __restrict__ Wxc, const float* __restrict__ Whc,
                               const float* __restrict__ Wxo, const float* __restrict__ Who,
                               unsigned short* __restrict__ outA,
                               unsigned short* __restrict__ outB) {
  const int totalA = B_DIM * K_DIM / 8;             // 2M 16B-units
  const int total  = totalA + N_DIM * K_DIM / 8;    // +1M
  for (int idx = blockIdx.x * blockDim.x + threadIdx.x; idx < total;
       idx += gridDim.x * blockDim.x) {
    const float* src;
    unsigned short* dst;
    if (idx < totalA) {
      int row = idx >> 8;              // K_DIM/8 = 256 units/row
      int col = (idx & 255) * 8;
      src = (col < I_DIM) ? (x + (size_t)row * I_DIM + col)
                          : (h + (size_t)row * H_DIM + (col - I_DIM));
      dst = outA + (size_t)idx * 8;
    } else {
      int u2 = idx - totalA;
      int r = u2 >> 8;
      int k = (u2 & 255) * 8;
      int g = (r >> 4) & 3;
      int hh = ((r >> 6) << 4) | (r & 15);
      src = (k < I_DIM)
          ? ((g == 0 ? Wxi : g == 1 ? Wxf : g == 2 ? Wxc : Wxo) + (size_t)hh * I_DIM + k)
          : ((g == 0 ? Whi : g == 1 ? Whf : g == 2 ? Whc : Who) + (size_t)hh * H_DIM + (k - I_DIM));
      dst = outB + (size_t)u2 * 8;
    }
    const float4* s4 = (const float4*)src;
    float4 v0 = s4[0], v1 = s4[1];
    bf16x8 o;
    o[0] = f2bf(v0.x); o[1] = f2bf(v0.y); o[2] = f2bf(v0.z); o[3] = f2bf(v0.w);
    o[4] = f2bf(v1.x); o[5] = f2bf(v1.y); o[6] = f2bf(v1.z); o[7] = f2bf(v1.w);
    *(bf16x8*)dst = o;
  }
}

// ---- GEMM 256x256 tile, BK=64, 8 waves (2Mx4N) ----
// LDS map (bytes): sA[buf][half] = buf*32768 + half*16384            (0..65536)
//                  sB[buf][half] = 65536 + buf*32768 + half*16384    (65536..131072)

#define STAGE(gptr, slotoff, ktile) do {                                          \
    int _ktc = (ktile) < NKT ? (ktile) : (NKT - 1);                               \
    const unsigned short* _g = (gptr) + (size_t)_ktc * 64;                        \
    __builtin_amdgcn_global_load_lds(                                             \
        (const __attribute__((address_space(1))) void*)_g,                        \
        (__attribute__((address_space(3))) void*)(lds + (slotoff) + wid * 1024),  \
        16, 0, 0);                                                                \
    __builtin_amdgcn_global_load_lds(                                             \
        (const __attribute__((address_space(1))) void*)(_g + (size_t)64 * K_DIM), \
        (__attribute__((address_space(3))) void*)(lds + (slotoff) + 8192 + wid * 1024), \
        16, 0, 0);                                                                \
  } while (0)

// phase (MH, kk): 16 independent MFMAs, acc rows MH*4..MH*4+3, one kk slice
#define MFMAP(MH, AR, BR)                                                         \
  _Pragma("unroll") for (int mf = 0; mf < 4; ++mf)                                \
  _Pragma("unroll") for (int nn = 0; nn < 4; ++nn)                                \
    acc[(MH)*4 + mf][nn] = __builtin_amdgcn_mfma_f32_16x16x32_bf16(               \
        AR[mf], BR[nn], acc[(MH)*4 + mf][nn], 0, 0, 0)

#define RD_AQ(DST, MH, KOFF, BO)                                                  \
  _Pragma("unroll") for (int mf = 0; mf < 4; ++mf)                                \
    DST[mf] = *(const bf16x8*)(ldsAr + (BO) + (MH)*8192 + mf * 2048 + (KOFF));

#define RD_BH(DST, KOFF, BO)                                                      \
  _Pragma("unroll") for (int nn = 0; nn < 4; ++nn)                                \
    DST[nn] = *(const bf16x8*)(ldsBr + (BO) + nn * 2048 + (KOFF));

#define KTILE(BUF, KT) do {                                                       \
    const int _bo = (BUF) * 32768;                                                \
    const int _bo1 = ((BUF) ^ 1) * 32768;                                         \
    /* p0 */                                                                      \
    __builtin_amdgcn_s_setprio(1);                                                \
    MFMAP(0, AQa, BHa);                                                           \
    __builtin_amdgcn_s_setprio(0);                                                \
    RD_AQ(AQb, 1, rd0, _bo);                                                      \
    __builtin_amdgcn_s_barrier();                                                 \
    /* p1 */                                                                      \
    __builtin_amdgcn_s_setprio(1);                                                \
    MFMAP(1, AQb, BHa);                                                           \
    __builtin_amdgcn_s_setprio(0);                                                \
    RD_BH(BHb, rd1, _bo);                                                         \
    RD_AQ(AQa, 0, rd1, _bo);                                                      \
    __builtin_amdgcn_s_barrier();                                                 \
    /* p2 */                                                                      \
    __builtin_amdgcn_s_setprio(1);                                                \
    MFMAP(0, AQa, BHb);                                                           \
    __builtin_amdgcn_s_setprio(0);                                                \
    RD_AQ(AQb, 1, rd1, _bo);                                                      \
    STAGE(gB0p, 65536 + _bo, (KT) + 2);                                           \
    STAGE(gB1p, 65536 + _bo + 16384, (KT) + 2);                                   \
    asm volatile("s_waitcnt vmcnt(4)" ::: "memory");                              \
    __builtin_amdgcn_s_barrier();                                                 \
    /* p3 */                                                                      \
    __builtin_amdgcn_s_setprio(1);                                                \
    MFMAP(1, AQb, BHb);                                                           \
    __builtin_amdgcn_s_setprio(0);                                                \
    RD_AQ(AQa, 0, rd0, _bo1);                                                     \
    RD_BH(BHa, rd0, _bo1);                                                        \
    STAGE(gA0p, _bo, (KT) + 2);                                                   \
    STAGE(gA1p, _bo + 16384, (KT) + 2);                                           \
    __builtin_amdgcn_s_barrier();                                                 \
  } while (0)

__launch_bounds__(512, 2)
__global__ void lstm_gemm_kernel(const unsigned short* __restrict__ A,
                                 const unsigned short* __restrict__ Bp,
                                 const float* __restrict__ c_prev,
                                 const float* __restrict__ bxi, const float* __restrict__ bhi,
                                 const float* __restrict__ bxf, const float* __restrict__ bhf,
                                 const float* __restrict__ bxc, const float* __restrict__ bhc,
                                 const float* __restrict__ bxo, const float* __restrict__ bho,
                                 float* __restrict__ out) {
  __shared__ __align__(16) char lds[131072];

  // XCD-aware bijective swizzle (512 % 8 == 0)
  const int nwg = gridDim.x;
  int bid = blockIdx.x;
  int q = nwg >> 3;
  int wg = (bid & 7) * q + (bid >> 3);
  int bm = wg >> 4;          // 32 M-tiles
  int bn = wg & 15;          // 16 N-tiles

  int tid = threadIdx.x;
  int lane = tid & 63;
  int wid = tid >> 6;        // 8 waves
  int wm = wid >> 2;         // 2 M-wave rows (128 rows each)
  int wn = wid & 3;          // 4 N-wave cols (64 cols each)

  // staging addresses: per half-tile, wave covers 8 rows x 128B; pre-swizzled
  // global source (rule #21): linear LDS dest, src chunk XOR row&7, same XOR on read.
  int srow = lane >> 3;                 // row within 8-row stripe
  int schunk = (lane & 7) ^ srow;       // swizzled 16B chunk
  const unsigned short* gA0p = A  + (size_t)(bm * 256 + wid * 8 + srow) * K_DIM + schunk * 8;
  const unsigned short* gA1p = gA0p + (size_t)128 * K_DIM;
  const unsigned short* gB0p = Bp + (size_t)(bn * 256 + wid * 8 + srow) * K_DIM + schunk * 8;
  const unsigned short* gB1p = gB0p + (size_t)128 * K_DIM;

  // LDS read bases (byte ptrs); frag row&7 == lane&7 for all fragment rows.
  int c15 = lane & 15;
  int kl = lane >> 4;                   // k-group 0..3
  const char* ldsAr = lds + wm * 16384 + c15 * 128;
  const char* ldsBr = lds + 65536 + (wn >> 1) * 16384 + ((wn & 1) * 64 + c15) * 128;
  int rd0 = ((kl) ^ (lane & 7)) << 4;         // kk=0 chunk
  int rd1 = ((4 | kl) ^ (lane & 7)) << 4;     // kk=1 chunk

  f32x4 acc[8][4];
  f32x4 zero = {0.f, 0.f, 0.f, 0.f};
#pragma unroll
  for (int m = 0; m < 8; ++m)
#pragma unroll
    for (int n = 0; n < 4; ++n) acc[m][n] = zero;

  bf16x8 AQa[4], AQb[4];   // A-quarter ping/pong (4 m-frags x 1 kk each)
  bf16x8 BHa[4], BHb[4];   // B kk-half ping/pong (4 n-frags each)

  // ---- prologue: stage tile0 -> buf0, tile1 -> buf1 (16 loads);
  // vmcnt(8) -> buf0 landed; pre-read p0 operands. ----
  STAGE(gA0p, 0, 0);
  STAGE(gA1p, 16384, 0);
  STAGE(gB0p, 65536, 0);
  STAGE(gB1p, 65536 + 16384, 0);
  STAGE(gA0p, 32768, 1);
  STAGE(gA1p, 32768 + 16384, 1);
  STAGE(gB0p, 65536 + 32768, 1);
  STAGE(gB1p, 65536 + 32768 + 16384, 1);
  asm volatile("s_waitcnt vmcnt(8)" ::: "memory");
  __builtin_amdgcn_s_barrier();
  RD_AQ(AQa, 0, rd0, 0);
  RD_BH(BHa, rd0, 0);

#pragma unroll 1
  for (int kt = 0; kt < NKT; kt += 2) {
    KTILE(0, kt);
    KTILE(1, kt + 1);
  }

  // ---- fused LSTM epilogue: lane owns hidden unit h; acc[mi][g][j] = gate g ----
  int h = (bn * 4 + wn) * 16 + c15;
  float bi = bxi[h] + bhi[h];
  float bf_ = bxf[h] + bhf[h];
  float bc = bxc[h] + bhc[h];
  float bo = bxo[h] + bho[h];
  int row0 = bm * 256 + wm * 128 + kl * 4;
#pragma unroll
  for (int mi = 0; mi < 8; ++mi) {
#pragma unroll
    for (int j = 0; j < 4; ++j) {
      int r = row0 + mi * 16 + j;
      size_t off = (size_t)r * H_DIM + h;
      float zi = acc[mi][0][j] + bi;
      float zf = acc[mi][1][j] + bf_;
      float zc = acc[mi][2][j] + bc;
      float zo = acc[mi][3][j] + bo;
      float ig = 1.f / (1.f + __expf(-zi));
      float fg = 1.f / (1.f + __expf(-zf));
      float e2 = __expf(-2.f * zc);
      float gg = (1.f - e2) / (1.f + e2);       // tanh(zc)
      float og = 1.f / (1.f + __expf(-zo));
      float cp = c_prev[off];
      float cn = fg * cp + ig * gg;
      float e2c = __expf(-2.f * cn);
      float th = (1.f - e2c) / (1.f + e2c);     // tanh(cn)
      out[off] = og * th;                        // h_new
      out[(size_t)B_DIM * H_DIM + off] = cn;     // c_new
    }
  }
}

extern "C" void kernel_launch(void* const* d_in, const int* in_sizes, int n_in,
                              void* d_out, int out_size, void* d_ws, size_t ws_size,
                              hipStream_t stream) {
  const float* x      = (const float*)d_in[0];
  const float* h_prev = (const float*)d_in[1];
  const float* c_prev = (const float*)d_in[2];
  const float* Wxi = (const float*)d_in[3];
  const float* Whi = (const float*)d_in[4];
  const float* Wxf = (const float*)d_in[5];
  const float* Whf = (const float*)d_in[6];
  const float* Wxc = (const float*)d_in[7];
  const float* Whc = (const float*)d_in[8];
  const float* Wxo = (const float*)d_in[9];
  const float* Who = (const float*)d_in[10];
  const float* bxi = (const float*)d_in[11];
  const float* bhi = (const float*)d_in[12];
  const float* bxf = (const float*)d_in[13];
  const float* bhf = (const float*)d_in[14];
  const float* bxc = (const float*)d_in[15];
  const float* bhc = (const float*)d_in[16];
  const float* bxo = (const float*)d_in[17];
  const float* bho = (const float*)d_in[18];

  unsigned short* Abf = (unsigned short*)d_ws;                                      // 32 MiB
  unsigned short* Bbf = (unsigned short*)((char*)d_ws + (size_t)B_DIM * K_DIM * 2); // +16 MiB

  pack_AB_kernel<<<2048, 256, 0, stream>>>(x, h_prev,
      Wxi, Whi, Wxf, Whf, Wxc, Whc, Wxo, Who, Abf, Bbf);
  lstm_gemm_kernel<<<512, 512, 0, stream>>>(Abf, Bbf, c_prev,
      bxi, bhi, bxf, bhf, bxc, bhc, bxo, bho, (float*)d_out);
}

// Round 15
// 150.650 us; speedup vs baseline: 1.1838x; 1.0053x over previous
//
#include <hip/hip_runtime.h>
#include <hip/hip_bf16.h>
#include <stdint.h>

// LSTM cell as one fused bf16 MFMA GEMM (R10/R7 schedule, minus non-load-bearing
// barriers): gates(8192 x 4096) = A(8192 x 2048) @ Bp(4096 x 2048)^T + fused
// LSTM epilogue. A = [x | h_prev] bf16. Bp rows gate-interleaved per 16 hidden
// units: packed row r = (h/16)*64 + g*16 + (h%16) -> wave's 4 N-frags = 4 gates
// of the same h -> epilogue fully in-register.
//
// ROUND 15: barrier-count cut 4 -> 2 per K-tile. Audit of the R10 timeline:
//  - p1-end barrier: LOAD-BEARING (protects STAGE B(T+2)->buf[T] @p2 from
//    sibling waves still reading buf[T] B-slots @p1).
//  - p2-end barrier (after vmcnt(4)): LOAD-BEARING (makes the per-wave vmcnt
//    guarantee collective before p3's cross-buffer reads — R11 lesson).
//  - p0-end, p3-end: NOT load-bearing — in their free-run regions all in-flight
//    LDS writes target the opposite buffer or slots whose last read is behind
//    a kept barrier. Removed.
// The two big free-run regions (p3+p0+p1) let waves slip -> cross-wave
// MFMA/LDS/VMEM overlap (m114) that lockstep suppressed. vmcnt counting is
// per-wave, program-order; asm "memory" clobbers pin stage-issue order.
// Everything else byte-identical to round 14 (session best 151.5us).

#define B_DIM 8192
#define I_DIM 1024
#define H_DIM 1024
#define K_DIM 2048   // I + H
#define N_DIM 4096   // 4 gates * H
#define NKT   32     // K_DIM / 64

typedef short bf16x8 __attribute__((ext_vector_type(8)));
typedef float f32x4 __attribute__((ext_vector_type(4)));

__device__ __forceinline__ unsigned short f2bf(float f) {
  unsigned int u = __float_as_uint(f);
  u += 0x7FFFu + ((u >> 16) & 1u);   // RNE
  return (unsigned short)(u >> 16);
}

// ---- merged pack: A = [x|h] -> bf16 row-major (B_DIM,K_DIM);
//      B = 8 weight mats -> bf16 (N_DIM,K_DIM), gate-interleaved rows ----
__global__ void pack_AB_kernel(const float* __restrict__ x, const float* __restrict__ h,
                               const float* __restrict__ Wxi, const float* __restrict__ Whi,
                               const float* __restrict__ Wxf, const float* __restrict__ Whf,
                               const float* __restrict__ Wxc, const float* __restrict__ Whc,
                               const float* __restrict__ Wxo, const float* __restrict__ Who,
                               unsigned short* __restrict__ outA,
                               unsigned short* __restrict__ outB) {
  const int totalA = B_DIM * K_DIM / 8;             // 2M 16B-units
  const int total  = totalA + N_DIM * K_DIM / 8;    // +1M
  for (int idx = blockIdx.x * blockDim.x + threadIdx.x; idx < total;
       idx += gridDim.x * blockDim.x) {
    const float* src;
    unsigned short* dst;
    if (idx < totalA) {
      int row = idx >> 8;              // K_DIM/8 = 256 units/row
      int col = (idx & 255) * 8;
      src = (col < I_DIM) ? (x + (size_t)row * I_DIM + col)
                          : (h + (size_t)row * H_DIM + (col - I_DIM));
      dst = outA + (size_t)idx * 8;
    } else {
      int u2 = idx - totalA;
      int r = u2 >> 8;
      int k = (u2 & 255) * 8;
      int g = (r >> 4) & 3;
      int hh = ((r >> 6) << 4) | (r & 15);
      src = (k < I_DIM)
          ? ((g == 0 ? Wxi : g == 1 ? Wxf : g == 2 ? Wxc : Wxo) + (size_t)hh * I_DIM + k)
          : ((g == 0 ? Whi : g == 1 ? Whf : g == 2 ? Whc : Who) + (size_t)hh * H_DIM + (k - I_DIM));
      dst = outB + (size_t)u2 * 8;
    }
    const float4* s4 = (const float4*)src;
    float4 v0 = s4[0], v1 = s4[1];
    bf16x8 o;
    o[0] = f2bf(v0.x); o[1] = f2bf(v0.y); o[2] = f2bf(v0.z); o[3] = f2bf(v0.w);
    o[4] = f2bf(v1.x); o[5] = f2bf(v1.y); o[6] = f2bf(v1.z); o[7] = f2bf(v1.w);
    *(bf16x8*)dst = o;
  }
}

// ---- GEMM 256x256 tile, BK=64, 8 waves (2Mx4N) ----
// LDS map (bytes): sA[buf][half] = buf*32768 + half*16384            (0..65536)
//                  sB[buf][half] = 65536 + buf*32768 + half*16384    (65536..131072)

#define STAGE(gptr, slotoff, ktile) do {                                          \
    int _ktc = (ktile) < NKT ? (ktile) : (NKT - 1);                               \
    const unsigned short* _g = (gptr) + (size_t)_ktc * 64;                        \
    __builtin_amdgcn_global_load_lds(                                             \
        (const __attribute__((address_space(1))) void*)_g,                        \
        (__attribute__((address_space(3))) void*)(lds + (slotoff) + wid * 1024),  \
        16, 0, 0);                                                                \
    __builtin_amdgcn_global_load_lds(                                             \
        (const __attribute__((address_space(1))) void*)(_g + (size_t)64 * K_DIM), \
        (__attribute__((address_space(3))) void*)(lds + (slotoff) + 8192 + wid * 1024), \
        16, 0, 0);                                                                \
  } while (0)

// phase (MH, kk): 16 independent MFMAs, acc rows MH*4..MH*4+3, one kk slice
#define MFMAP(MH, AR, BR)                                                         \
  _Pragma("unroll") for (int mf = 0; mf < 4; ++mf)                                \
  _Pragma("unroll") for (int nn = 0; nn < 4; ++nn)                                \
    acc[(MH)*4 + mf][nn] = __builtin_amdgcn_mfma_f32_16x16x32_bf16(               \
        AR[mf], BR[nn], acc[(MH)*4 + mf][nn], 0, 0, 0)

#define RD_AQ(DST, MH, KOFF, BO)                                                  \
  _Pragma("unroll") for (int mf = 0; mf < 4; ++mf)                                \
    DST[mf] = *(const bf16x8*)(ldsAr + (BO) + (MH)*8192 + mf * 2048 + (KOFF));

#define RD_BH(DST, KOFF, BO)                                                      \
  _Pragma("unroll") for (int nn = 0; nn < 4; ++nn)                                \
    DST[nn] = *(const bf16x8*)(ldsBr + (BO) + nn * 2048 + (KOFF));

#define KTILE(BUF, KT) do {                                                       \
    const int _bo = (BUF) * 32768;                                                \
    const int _bo1 = ((BUF) ^ 1) * 32768;                                         \
    /* p0 (free-run, no trailing barrier) */                                      \
    __builtin_amdgcn_s_setprio(1);                                                \
    MFMAP(0, AQa, BHa);                                                           \
    __builtin_amdgcn_s_setprio(0);                                                \
    RD_AQ(AQb, 1, rd0, _bo);                                                      \
    /* p1 */                                                                      \
    __builtin_amdgcn_s_setprio(1);                                                \
    MFMAP(1, AQb, BHa);                                                           \
    __builtin_amdgcn_s_setprio(0);                                                \
    RD_BH(BHb, rd1, _bo);                                                         \
    RD_AQ(AQa, 0, rd1, _bo);                                                      \
    __builtin_amdgcn_s_barrier();   /* LOAD-BEARING: B-slots of buf[T] fully */   \
    /* p2: stage B(T+2) into buf[T]   read after this point                 */    \
    __builtin_amdgcn_s_setprio(1);                                                \
    MFMAP(0, AQa, BHb);                                                           \
    __builtin_amdgcn_s_setprio(0);                                                \
    RD_AQ(AQb, 1, rd1, _bo);                                                      \
    STAGE(gB0p, 65536 + _bo, (KT) + 2);                                           \
    STAGE(gB1p, 65536 + _bo + 16384, (KT) + 2);                                   \
    asm volatile("s_waitcnt vmcnt(4)" ::: "memory");                              \
    __builtin_amdgcn_s_barrier();   /* LOAD-BEARING: makes vmcnt collective */    \
    /* p3 (free-run, no trailing barrier): cross-buffer reads of T+1 */           \
    __builtin_amdgcn_s_setprio(1);                                                \
    MFMAP(1, AQb, BHb);                                                           \
    __builtin_amdgcn_s_setprio(0);                                                \
    RD_AQ(AQa, 0, rd0, _bo1);                                                     \
    RD_BH(BHa, rd0, _bo1);                                                        \
    STAGE(gA0p, _bo, (KT) + 2);                                                   \
    STAGE(gA1p, _bo + 16384, (KT) + 2);                                           \
  } while (0)

__launch_bounds__(512, 2)
__global__ void lstm_gemm_kernel(const unsigned short* __restrict__ A,
                                 const unsigned short* __restrict__ Bp,
                                 const float* __restrict__ c_prev,
                                 const float* __restrict__ bxi, const float* __restrict__ bhi,
                                 const float* __restrict__ bxf, const float* __restrict__ bhf,
                                 const float* __restrict__ bxc, const float* __restrict__ bhc,
                                 const float* __restrict__ bxo, const float* __restrict__ bho,
                                 float* __restrict__ out) {
  __shared__ __align__(16) char lds[131072];

  // XCD-aware bijective swizzle (512 % 8 == 0)
  const int nwg = gridDim.x;
  int bid = blockIdx.x;
  int q = nwg >> 3;
  int wg = (bid & 7) * q + (bid >> 3);
  int bm = wg >> 4;          // 32 M-tiles
  int bn = wg & 15;          // 16 N-tiles

  int tid = threadIdx.x;
  int lane = tid & 63;
  int wid = tid >> 6;        // 8 waves
  int wm = wid >> 2;         // 2 M-wave rows (128 rows each)
  int wn = wid & 3;          // 4 N-wave cols (64 cols each)

  // staging addresses: per half-tile, wave covers 8 rows x 128B; pre-swizzled
  // global source (rule #21): linear LDS dest, src chunk XOR row&7, same XOR on read.
  int srow = lane >> 3;                 // row within 8-row stripe
  int schunk = (lane & 7) ^ srow;       // swizzled 16B chunk
  const unsigned short* gA0p = A  + (size_t)(bm * 256 + wid * 8 + srow) * K_DIM + schunk * 8;
  const unsigned short* gA1p = gA0p + (size_t)128 * K_DIM;
  const unsigned short* gB0p = Bp + (size_t)(bn * 256 + wid * 8 + srow) * K_DIM + schunk * 8;
  const unsigned short* gB1p = gB0p + (size_t)128 * K_DIM;

  // LDS read bases (byte ptrs); frag row&7 == lane&7 for all fragment rows.
  int c15 = lane & 15;
  int kl = lane >> 4;                   // k-group 0..3
  const char* ldsAr = lds + wm * 16384 + c15 * 128;
  const char* ldsBr = lds + 65536 + (wn >> 1) * 16384 + ((wn & 1) * 64 + c15) * 128;
  int rd0 = ((kl) ^ (lane & 7)) << 4;         // kk=0 chunk
  int rd1 = ((4 | kl) ^ (lane & 7)) << 4;     // kk=1 chunk

  f32x4 acc[8][4];
  f32x4 zero = {0.f, 0.f, 0.f, 0.f};
#pragma unroll
  for (int m = 0; m < 8; ++m)
#pragma unroll
    for (int n = 0; n < 4; ++n) acc[m][n] = zero;

  bf16x8 AQa[4], AQb[4];   // A-quarter ping/pong (4 m-frags x 1 kk each)
  bf16x8 BHa[4], BHb[4];   // B kk-half ping/pong (4 n-frags each)

  // ---- prologue: stage tile0 -> buf0, tile1 -> buf1 (16 loads);
  // vmcnt(8) -> buf0 landed collectively after barrier; pre-read p0 operands. ----
  STAGE(gA0p, 0, 0);
  STAGE(gA1p, 16384, 0);
  STAGE(gB0p, 65536, 0);
  STAGE(gB1p, 65536 + 16384, 0);
  STAGE(gA0p, 32768, 1);
  STAGE(gA1p, 32768 + 16384, 1);
  STAGE(gB0p, 65536 + 32768, 1);
  STAGE(gB1p, 65536 + 32768 + 16384, 1);
  asm volatile("s_waitcnt vmcnt(8)" ::: "memory");
  __builtin_amdgcn_s_barrier();
  RD_AQ(AQa, 0, rd0, 0);
  RD_BH(BHa, rd0, 0);

#pragma unroll 1
  for (int kt = 0; kt < NKT; kt += 2) {
    KTILE(0, kt);
    KTILE(1, kt + 1);
  }

  // ---- fused LSTM epilogue: lane owns hidden unit h; acc[mi][g][j] = gate g ----
  int h = (bn * 4 + wn) * 16 + c15;
  float bi = bxi[h] + bhi[h];
  float bf_ = bxf[h] + bhf[h];
  float bc = bxc[h] + bhc[h];
  float bo = bxo[h] + bho[h];
  int row0 = bm * 256 + wm * 128 + kl * 4;
#pragma unroll
  for (int mi = 0; mi < 8; ++mi) {
#pragma unroll
    for (int j = 0; j < 4; ++j) {
      int r = row0 + mi * 16 + j;
      size_t off = (size_t)r * H_DIM + h;
      float zi = acc[mi][0][j] + bi;
      float zf = acc[mi][1][j] + bf_;
      float zc = acc[mi][2][j] + bc;
      float zo = acc[mi][3][j] + bo;
      float ig = 1.f / (1.f + __expf(-zi));
      float fg = 1.f / (1.f + __expf(-zf));
      float e2 = __expf(-2.f * zc);
      float gg = (1.f - e2) / (1.f + e2);       // tanh(zc)
      float og = 1.f / (1.f + __expf(-zo));
      float cp = c_prev[off];
      float cn = fg * cp + ig * gg;
      float e2c = __expf(-2.f * cn);
      float th = (1.f - e2c) / (1.f + e2c);     // tanh(cn)
      out[off] = og * th;                        // h_new
      out[(size_t)B_DIM * H_DIM + off] = cn;     // c_new
    }
  }
}

extern "C" void kernel_launch(void* const* d_in, const int* in_sizes, int n_in,
                              void* d_out, int out_size, void* d_ws, size_t ws_size,
                              hipStream_t stream) {
  const float* x      = (const float*)d_in[0];
  const float* h_prev = (const float*)d_in[1];
  const float* c_prev = (const float*)d_in[2];
  const float* Wxi = (const float*)d_in[3];
  const float* Whi = (const float*)d_in[4];
  const float* Wxf = (const float*)d_in[5];
  const float* Whf = (const float*)d_in[6];
  const float* Wxc = (const float*)d_in[7];
  const float* Whc = (const float*)d_in[8];
  const float* Wxo = (const float*)d_in[9];
  const float* Who = (const float*)d_in[10];
  const float* bxi = (const float*)d_in[11];
  const float* bhi = (const float*)d_in[12];
  const float* bxf = (const float*)d_in[13];
  const float* bhf = (const float*)d_in[14];
  const float* bxc = (const float*)d_in[15];
  const float* bhc = (const float*)d_in[16];
  const float* bxo = (const float*)d_in[17];
  const float* bho = (const float*)d_in[18];

  unsigned short* Abf = (unsigned short*)d_ws;                                      // 32 MiB
  unsigned short* Bbf = (unsigned short*)((char*)d_ws + (size_t)B_DIM * K_DIM * 2); // +16 MiB

  pack_AB_kernel<<<2048, 256, 0, stream>>>(x, h_prev,
      Wxi, Whi, Wxf, Whf, Wxc, Whc, Wxo, Who, Abf, Bbf);
  lstm_gemm_kernel<<<512, 512, 0, stream>>>(Abf, Bbf, c_prev,
      bxi, bhi, bxf, bhf, bxc, bhc, bxo, bho, (float*)d_out);
}